// Round 3
// baseline (456.745 us; speedup 1.0000x reference)
//
#include <hip/hip_runtime.h>

// InstanceWiseAveragePooling on MI355X.
// inst in {0,1,2} covers every pixel and masks are disjoint, so
// out[p,ch] = mean[inst[p]] where mean[c] = sum(feats over class-c pixels,
// all 3 channels) / (3 * pixel_count_c). Original feats never survive.
//
// Traffic plan (floor = feats 201 + inst 67 + out 201 = 470 MB):
//   1) reduce_k:   reads feats+inst (268 MB), writes 2-bit packed class
//                  codes (4 MB) + per-block double partials. fp64 accum
//                  (50M-element sums; fp32 would blow the 4.5e-6 absmax).
//   2) finalize_k: 1 block: 2048 partials -> float mean[3].
//   3) scatter_k:  reads codes (4 MB), writes out (201 MB).
// Non-temporal on all streaming traffic (zero reuse). Native ext_vector
// types because __builtin_nontemporal_* rejects HIP_vector_type structs.

#define RBLK 2048

typedef float vfloat4 __attribute__((ext_vector_type(4)));
typedef int vint4 __attribute__((ext_vector_type(4)));

__device__ inline vfloat4 ntload_f4(const float* p) {
    return __builtin_nontemporal_load((const vfloat4*)p);
}
__device__ inline vint4 ntload_i4(const int* p) {
    return __builtin_nontemporal_load((const vint4*)p);
}
__device__ inline void ntstore_f4(float* p, vfloat4 v) {
    __builtin_nontemporal_store(v, (vfloat4*)p);
}

__device__ inline double wred_d(double v) {
#pragma unroll
    for (int off = 32; off; off >>= 1) v += __shfl_down(v, off, 64);
    return v;
}
__device__ inline unsigned wred_u(unsigned v) {
#pragma unroll
    for (int off = 32; off; off >>= 1) v += __shfl_down(v, off, 64);
    return v;
}

__global__ __launch_bounds__(256) void reduce_k(const float* __restrict__ feats,
                                                const int* __restrict__ inst,
                                                double* __restrict__ psum,
                                                unsigned* __restrict__ pcnt,
                                                unsigned char* __restrict__ codes,
                                                int npix4) {
    int tid = blockIdx.x * 256 + threadIdx.x;
    int stride = gridDim.x * 256;
    double s0 = 0.0, s1 = 0.0, s2 = 0.0;
    unsigned c0 = 0, c1 = 0, c2 = 0;
    for (int i = tid; i < npix4; i += stride) {
        vint4 cls = ntload_i4(inst + (size_t)i * 4);
        const float* f = feats + (size_t)i * 12;
        vfloat4 a = ntload_f4(f + 0);
        vfloat4 b = ntload_f4(f + 4);
        vfloat4 c = ntload_f4(f + 8);
        // pixel 0: a.x a.y a.z | pixel 1: a.w b.x b.y
        // pixel 2: b.z b.w c.x | pixel 3: c.y c.z c.w
        double d0 = (double)(a.x + a.y + a.z);
        double d1 = (double)(a.w + b.x + b.y);
        double d2 = (double)(b.z + b.w + c.x);
        double d3 = (double)(c.y + c.z + c.w);
        s0 += (cls.x == 0) ? d0 : 0.0;
        s1 += (cls.x == 1) ? d0 : 0.0;
        s2 += (cls.x == 2) ? d0 : 0.0;
        s0 += (cls.y == 0) ? d1 : 0.0;
        s1 += (cls.y == 1) ? d1 : 0.0;
        s2 += (cls.y == 2) ? d1 : 0.0;
        s0 += (cls.z == 0) ? d2 : 0.0;
        s1 += (cls.z == 1) ? d2 : 0.0;
        s2 += (cls.z == 2) ? d2 : 0.0;
        s0 += (cls.w == 0) ? d3 : 0.0;
        s1 += (cls.w == 1) ? d3 : 0.0;
        s2 += (cls.w == 2) ? d3 : 0.0;
        c0 += (unsigned)(cls.x == 0) + (unsigned)(cls.y == 0) +
              (unsigned)(cls.z == 0) + (unsigned)(cls.w == 0);
        c1 += (unsigned)(cls.x == 1) + (unsigned)(cls.y == 1) +
              (unsigned)(cls.z == 1) + (unsigned)(cls.w == 1);
        c2 += (unsigned)(cls.x == 2) + (unsigned)(cls.y == 2) +
              (unsigned)(cls.z == 2) + (unsigned)(cls.w == 2);
        // 2-bit packed classes, 4 pixels/byte
        unsigned char code = (unsigned char)((cls.x & 3) | ((cls.y & 3) << 2) |
                                             ((cls.z & 3) << 4) | ((cls.w & 3) << 6));
        __builtin_nontemporal_store(code, &codes[i]);
    }
    s0 = wred_d(s0); s1 = wred_d(s1); s2 = wred_d(s2);
    c0 = wred_u(c0); c1 = wred_u(c1); c2 = wred_u(c2);

    __shared__ double ls[4][3];
    __shared__ unsigned lc[4][3];
    int wid = threadIdx.x >> 6;
    int lane = threadIdx.x & 63;
    if (lane == 0) {
        ls[wid][0] = s0; ls[wid][1] = s1; ls[wid][2] = s2;
        lc[wid][0] = c0; lc[wid][1] = c1; lc[wid][2] = c2;
    }
    __syncthreads();
    if (threadIdx.x < 3) {
        int c = threadIdx.x;
        double s = ls[0][c] + ls[1][c] + ls[2][c] + ls[3][c];
        unsigned cc = lc[0][c] + lc[1][c] + lc[2][c] + lc[3][c];
        psum[blockIdx.x * 3 + c] = s;
        pcnt[blockIdx.x * 3 + c] = cc;
    }
}

__global__ __launch_bounds__(256) void finalize_k(const double* __restrict__ psum,
                                                  const unsigned* __restrict__ pcnt,
                                                  float* __restrict__ mean,
                                                  int nblk) {
    double s0 = 0.0, s1 = 0.0, s2 = 0.0;
    unsigned c0 = 0, c1 = 0, c2 = 0;
    for (int i = threadIdx.x; i < nblk; i += 256) {
        s0 += psum[i * 3 + 0]; s1 += psum[i * 3 + 1]; s2 += psum[i * 3 + 2];
        c0 += pcnt[i * 3 + 0]; c1 += pcnt[i * 3 + 1]; c2 += pcnt[i * 3 + 2];
    }
    s0 = wred_d(s0); s1 = wred_d(s1); s2 = wred_d(s2);
    c0 = wred_u(c0); c1 = wred_u(c1); c2 = wred_u(c2);

    __shared__ double ls[4][3];
    __shared__ unsigned lc[4][3];
    int wid = threadIdx.x >> 6;
    int lane = threadIdx.x & 63;
    if (lane == 0) {
        ls[wid][0] = s0; ls[wid][1] = s1; ls[wid][2] = s2;
        lc[wid][0] = c0; lc[wid][1] = c1; lc[wid][2] = c2;
    }
    __syncthreads();
    if (threadIdx.x < 3) {
        int c = threadIdx.x;
        double s = ls[0][c] + ls[1][c] + ls[2][c] + ls[3][c];
        unsigned cc = lc[0][c] + lc[1][c] + lc[2][c] + lc[3][c];
        // count includes the 3-channel broadcast in the reference
        mean[c] = (float)(s / (3.0 * (double)cc));
    }
}

__global__ __launch_bounds__(256) void scatter_k(const unsigned char* __restrict__ codes,
                                                 const float* __restrict__ mean,
                                                 float* __restrict__ out,
                                                 int npix4) {
    int i = blockIdx.x * 256 + threadIdx.x;
    if (i >= npix4) return;
    float m0 = mean[0], m1 = mean[1], m2 = mean[2];
    unsigned c = codes[i];
    unsigned kx = c & 3, ky = (c >> 2) & 3, kz = (c >> 4) & 3, kw = (c >> 6) & 3;
    float vx = (kx == 1) ? m1 : ((kx == 2) ? m2 : m0);
    float vy = (ky == 1) ? m1 : ((ky == 2) ? m2 : m0);
    float vz = (kz == 1) ? m1 : ((kz == 2) ? m2 : m0);
    float vw = (kw == 1) ? m1 : ((kw == 2) ? m2 : m0);
    float* o = out + (size_t)i * 12;
    vfloat4 o0 = {vx, vx, vx, vy};
    vfloat4 o1 = {vy, vy, vz, vz};
    vfloat4 o2 = {vz, vw, vw, vw};
    ntstore_f4(o + 0, o0);
    ntstore_f4(o + 4, o1);
    ntstore_f4(o + 8, o2);
}

extern "C" void kernel_launch(void* const* d_in, const int* in_sizes, int n_in,
                              void* d_out, int out_size, void* d_ws, size_t ws_size,
                              hipStream_t stream) {
    const float* feats = (const float*)d_in[0];
    const int* inst = (const int*)d_in[1];
    float* out = (float*)d_out;

    int npix = in_sizes[1];        // 16*1024*1024, divisible by 4
    int npix4 = npix >> 2;

    double* psum = (double*)d_ws;                       // RBLK*3 doubles
    unsigned* pcnt = (unsigned*)(psum + RBLK * 3);      // RBLK*3 uints
    float* mean = (float*)(pcnt + RBLK * 3);            // 3 floats
    unsigned char* codes = (unsigned char*)(mean + 4);  // npix4 bytes (4 MB)

    reduce_k<<<RBLK, 256, 0, stream>>>(feats, inst, psum, pcnt, codes, npix4);
    finalize_k<<<1, 256, 0, stream>>>(psum, pcnt, mean, RBLK);
    scatter_k<<<(npix4 + 255) / 256, 256, 0, stream>>>(codes, mean, out, npix4);
}

// Round 4
// 415.904 us; speedup vs baseline: 1.0982x; 1.0982x over previous
//
#include <hip/hip_runtime.h>

// InstanceWiseAveragePooling on MI355X.
// inst in {0,1,2} covers every pixel and masks are disjoint, so
// out[p,ch] = mean[inst[p]] where mean[c] = sum(feats over class-c pixels,
// all 3 channels) / (3 * pixel_count_c). Original feats never survive.
//
// Traffic plan (floor = feats 201 + inst 67 + out 201 = 470 MB):
//   1) reduce_k:   reads feats+inst (268 MB), writes 2-bit packed class
//                  codes (4 MB) + per-block double partials. fp64 accum
//                  (50M-element sums; fp32 would blow the 4.5e-6 absmax).
//   2) finalize_k: 1 block: 2048 partials -> float mean[3].
//   3) scatter_k:  reads codes (4 MB), writes out (201 MB), 8 pix/thread.
//
// R3 lesson: NO non-temporal anywhere — harness restores inputs right
// before each replay, so feats/inst are L3-warm; nt loads forfeit those
// hits (cost ~50 us). Plain cached loads/stores throughout.

#define RBLK 2048

typedef float vfloat4 __attribute__((ext_vector_type(4)));
typedef int vint4 __attribute__((ext_vector_type(4)));

__device__ inline double wred_d(double v) {
#pragma unroll
    for (int off = 32; off; off >>= 1) v += __shfl_down(v, off, 64);
    return v;
}
__device__ inline unsigned wred_u(unsigned v) {
#pragma unroll
    for (int off = 32; off; off >>= 1) v += __shfl_down(v, off, 64);
    return v;
}

__global__ __launch_bounds__(256) void reduce_k(const float* __restrict__ feats,
                                                const int* __restrict__ inst,
                                                double* __restrict__ psum,
                                                unsigned* __restrict__ pcnt,
                                                unsigned char* __restrict__ codes,
                                                int npix4) {
    int tid = blockIdx.x * 256 + threadIdx.x;
    int stride = gridDim.x * 256;
    double s0 = 0.0, s1 = 0.0, s2 = 0.0;
    unsigned c0 = 0, c1 = 0, c2 = 0;
    const vint4* inst4 = (const vint4*)inst;
    for (int i = tid; i < npix4; i += stride) {
        vint4 cls = inst4[i];
        const vfloat4* f = (const vfloat4*)(feats + (size_t)i * 12);
        vfloat4 a = f[0], b = f[1], c = f[2];
        // pixel 0: a.x a.y a.z | pixel 1: a.w b.x b.y
        // pixel 2: b.z b.w c.x | pixel 3: c.y c.z c.w
        double d0 = (double)(a.x + a.y + a.z);
        double d1 = (double)(a.w + b.x + b.y);
        double d2 = (double)(b.z + b.w + c.x);
        double d3 = (double)(c.y + c.z + c.w);
        s0 += (cls.x == 0) ? d0 : 0.0;
        s1 += (cls.x == 1) ? d0 : 0.0;
        s2 += (cls.x == 2) ? d0 : 0.0;
        s0 += (cls.y == 0) ? d1 : 0.0;
        s1 += (cls.y == 1) ? d1 : 0.0;
        s2 += (cls.y == 2) ? d1 : 0.0;
        s0 += (cls.z == 0) ? d2 : 0.0;
        s1 += (cls.z == 1) ? d2 : 0.0;
        s2 += (cls.z == 2) ? d2 : 0.0;
        s0 += (cls.w == 0) ? d3 : 0.0;
        s1 += (cls.w == 1) ? d3 : 0.0;
        s2 += (cls.w == 2) ? d3 : 0.0;
        c0 += (unsigned)(cls.x == 0) + (unsigned)(cls.y == 0) +
              (unsigned)(cls.z == 0) + (unsigned)(cls.w == 0);
        c1 += (unsigned)(cls.x == 1) + (unsigned)(cls.y == 1) +
              (unsigned)(cls.z == 1) + (unsigned)(cls.w == 1);
        c2 += (unsigned)(cls.x == 2) + (unsigned)(cls.y == 2) +
              (unsigned)(cls.z == 2) + (unsigned)(cls.w == 2);
        // 2-bit packed classes, 4 pixels/byte
        codes[i] = (unsigned char)((cls.x & 3) | ((cls.y & 3) << 2) |
                                   ((cls.z & 3) << 4) | ((cls.w & 3) << 6));
    }
    s0 = wred_d(s0); s1 = wred_d(s1); s2 = wred_d(s2);
    c0 = wred_u(c0); c1 = wred_u(c1); c2 = wred_u(c2);

    __shared__ double ls[4][3];
    __shared__ unsigned lc[4][3];
    int wid = threadIdx.x >> 6;
    int lane = threadIdx.x & 63;
    if (lane == 0) {
        ls[wid][0] = s0; ls[wid][1] = s1; ls[wid][2] = s2;
        lc[wid][0] = c0; lc[wid][1] = c1; lc[wid][2] = c2;
    }
    __syncthreads();
    if (threadIdx.x < 3) {
        int c = threadIdx.x;
        double s = ls[0][c] + ls[1][c] + ls[2][c] + ls[3][c];
        unsigned cc = lc[0][c] + lc[1][c] + lc[2][c] + lc[3][c];
        psum[blockIdx.x * 3 + c] = s;
        pcnt[blockIdx.x * 3 + c] = cc;
    }
}

__global__ __launch_bounds__(256) void finalize_k(const double* __restrict__ psum,
                                                  const unsigned* __restrict__ pcnt,
                                                  float* __restrict__ mean,
                                                  int nblk) {
    double s0 = 0.0, s1 = 0.0, s2 = 0.0;
    unsigned c0 = 0, c1 = 0, c2 = 0;
    for (int i = threadIdx.x; i < nblk; i += 256) {
        s0 += psum[i * 3 + 0]; s1 += psum[i * 3 + 1]; s2 += psum[i * 3 + 2];
        c0 += pcnt[i * 3 + 0]; c1 += pcnt[i * 3 + 1]; c2 += pcnt[i * 3 + 2];
    }
    s0 = wred_d(s0); s1 = wred_d(s1); s2 = wred_d(s2);
    c0 = wred_u(c0); c1 = wred_u(c1); c2 = wred_u(c2);

    __shared__ double ls[4][3];
    __shared__ unsigned lc[4][3];
    int wid = threadIdx.x >> 6;
    int lane = threadIdx.x & 63;
    if (lane == 0) {
        ls[wid][0] = s0; ls[wid][1] = s1; ls[wid][2] = s2;
        lc[wid][0] = c0; lc[wid][1] = c1; lc[wid][2] = c2;
    }
    __syncthreads();
    if (threadIdx.x < 3) {
        int c = threadIdx.x;
        double s = ls[0][c] + ls[1][c] + ls[2][c] + ls[3][c];
        unsigned cc = lc[0][c] + lc[1][c] + lc[2][c] + lc[3][c];
        // count includes the 3-channel broadcast in the reference
        mean[c] = (float)(s / (3.0 * (double)cc));
    }
}

// 8 pixels per thread: 2 code bytes (ushort load), 24 output floats.
__global__ __launch_bounds__(256) void scatter_k(const unsigned short* __restrict__ codes2,
                                                 const float* __restrict__ mean,
                                                 float* __restrict__ out,
                                                 int npix8) {
    int i = blockIdx.x * 256 + threadIdx.x;
    if (i >= npix8) return;
    float m0 = mean[0], m1 = mean[1], m2 = mean[2];
    unsigned cc = codes2[i];  // 8 pixels, 2 bits each
    float v[8];
#pragma unroll
    for (int p = 0; p < 8; ++p) {
        unsigned k = (cc >> (2 * p)) & 3;
        v[p] = (k == 1) ? m1 : ((k == 2) ? m2 : m0);
    }
    vfloat4* o = (vfloat4*)(out + (size_t)i * 24);
    vfloat4 o0 = {v[0], v[0], v[0], v[1]};
    vfloat4 o1 = {v[1], v[1], v[2], v[2]};
    vfloat4 o2 = {v[2], v[3], v[3], v[3]};
    vfloat4 o3 = {v[4], v[4], v[4], v[5]};
    vfloat4 o4 = {v[5], v[5], v[6], v[6]};
    vfloat4 o5 = {v[6], v[7], v[7], v[7]};
    o[0] = o0; o[1] = o1; o[2] = o2; o[3] = o3; o[4] = o4; o[5] = o5;
}

extern "C" void kernel_launch(void* const* d_in, const int* in_sizes, int n_in,
                              void* d_out, int out_size, void* d_ws, size_t ws_size,
                              hipStream_t stream) {
    const float* feats = (const float*)d_in[0];
    const int* inst = (const int*)d_in[1];
    float* out = (float*)d_out;

    int npix = in_sizes[1];        // 16*1024*1024, divisible by 8
    int npix4 = npix >> 2;
    int npix8 = npix >> 3;

    double* psum = (double*)d_ws;                       // RBLK*3 doubles
    unsigned* pcnt = (unsigned*)(psum + RBLK * 3);      // RBLK*3 uints
    float* mean = (float*)(pcnt + RBLK * 3);            // 3 floats (+pad)
    unsigned char* codes = (unsigned char*)(mean + 4);  // npix4 bytes (4 MB), 2B-aligned

    reduce_k<<<RBLK, 256, 0, stream>>>(feats, inst, psum, pcnt, codes, npix4);
    finalize_k<<<1, 256, 0, stream>>>(psum, pcnt, mean, RBLK);
    scatter_k<<<(npix8 + 255) / 256, 256, 0, stream>>>((const unsigned short*)codes, mean,
                                                       out, npix8);
}

// Round 5
// 414.181 us; speedup vs baseline: 1.1028x; 1.0042x over previous
//
#include <hip/hip_runtime.h>

// InstanceWiseAveragePooling on MI355X.
// inst in {0,1,2} covers every pixel and masks are disjoint, so
// out[p,ch] = mean[inst[p]] where mean[c] = sum(feats over class-c pixels,
// all 3 channels) / (3 * pixel_count_c). Original feats never survive.
//
// Two kernels, same 2048-block geometry (codes stay XCD-L2-local):
//   1) reduce_k:  8 pixels/thread-iter (96B feats + 32B inst), fp64 accum
//                 (50M-element sums; fp32 would blow the 4.5e-6 absmax),
//                 writes 2-bit packed codes (4 MB) + per-block partials.
//   2) scatter_k: EVERY block redundantly reduces the 2048x3 partials to
//                 mean[3] (73 KB, L2/L3-hit, ~8 iters/thread — replaces the
//                 single-block finalize kernel whose ~10us serial bubble +
//                 launch gap we measured as part of a ~40us structural gap),
//                 then writes out (201 MB) at 8 pixels/thread.
//
// R3 lesson: NO non-temporal anywhere — harness restores inputs right
// before each replay, so inputs are L3-warm; nt loads forfeit those hits
// (cost ~50 us measured). Plain cached loads/stores throughout.

#define RBLK 2048

typedef float vfloat4 __attribute__((ext_vector_type(4)));
typedef int vint4 __attribute__((ext_vector_type(4)));

__device__ inline double wred_d(double v) {
#pragma unroll
    for (int off = 32; off; off >>= 1) v += __shfl_down(v, off, 64);
    return v;
}
__device__ inline unsigned wred_u(unsigned v) {
#pragma unroll
    for (int off = 32; off; off >>= 1) v += __shfl_down(v, off, 64);
    return v;
}

// Accumulate one 4-pixel group (int4 classes, 3x float4 feats) into fp64 sums.
__device__ inline void acc_group(vint4 cls, vfloat4 a, vfloat4 b, vfloat4 c,
                                 double& s0, double& s1, double& s2,
                                 unsigned& c0, unsigned& c1, unsigned& c2) {
    // pixel 0: a.x a.y a.z | pixel 1: a.w b.x b.y
    // pixel 2: b.z b.w c.x | pixel 3: c.y c.z c.w
    double d0 = (double)(a.x + a.y + a.z);
    double d1 = (double)(a.w + b.x + b.y);
    double d2 = (double)(b.z + b.w + c.x);
    double d3 = (double)(c.y + c.z + c.w);
    s0 += (cls.x == 0) ? d0 : 0.0;
    s1 += (cls.x == 1) ? d0 : 0.0;
    s2 += (cls.x == 2) ? d0 : 0.0;
    s0 += (cls.y == 0) ? d1 : 0.0;
    s1 += (cls.y == 1) ? d1 : 0.0;
    s2 += (cls.y == 2) ? d1 : 0.0;
    s0 += (cls.z == 0) ? d2 : 0.0;
    s1 += (cls.z == 1) ? d2 : 0.0;
    s2 += (cls.z == 2) ? d2 : 0.0;
    s0 += (cls.w == 0) ? d3 : 0.0;
    s1 += (cls.w == 1) ? d3 : 0.0;
    s2 += (cls.w == 2) ? d3 : 0.0;
    c0 += (unsigned)(cls.x == 0) + (unsigned)(cls.y == 0) +
          (unsigned)(cls.z == 0) + (unsigned)(cls.w == 0);
    c1 += (unsigned)(cls.x == 1) + (unsigned)(cls.y == 1) +
          (unsigned)(cls.z == 1) + (unsigned)(cls.w == 1);
    c2 += (unsigned)(cls.x == 2) + (unsigned)(cls.y == 2) +
          (unsigned)(cls.z == 2) + (unsigned)(cls.w == 2);
}

__device__ inline unsigned pack4(vint4 cls) {
    return (unsigned)((cls.x & 3) | ((cls.y & 3) << 2) |
                      ((cls.z & 3) << 4) | ((cls.w & 3) << 6));
}

__global__ __launch_bounds__(256) void reduce_k(const float* __restrict__ feats,
                                                const int* __restrict__ inst,
                                                double* __restrict__ psum,
                                                unsigned* __restrict__ pcnt,
                                                unsigned short* __restrict__ codes2,
                                                int npix8) {
    int tid = blockIdx.x * 256 + threadIdx.x;
    int stride = gridDim.x * 256;
    double s0 = 0.0, s1 = 0.0, s2 = 0.0;
    unsigned c0 = 0, c1 = 0, c2 = 0;
    const vint4* inst4 = (const vint4*)inst;
    for (int i = tid; i < npix8; i += stride) {
        vint4 clsA = inst4[(size_t)i * 2 + 0];
        vint4 clsB = inst4[(size_t)i * 2 + 1];
        const vfloat4* f = (const vfloat4*)(feats + (size_t)i * 24);
        vfloat4 fa0 = f[0], fa1 = f[1], fa2 = f[2];
        vfloat4 fb0 = f[3], fb1 = f[4], fb2 = f[5];
        acc_group(clsA, fa0, fa1, fa2, s0, s1, s2, c0, c1, c2);
        acc_group(clsB, fb0, fb1, fb2, s0, s1, s2, c0, c1, c2);
        codes2[i] = (unsigned short)(pack4(clsA) | (pack4(clsB) << 8));
    }
    s0 = wred_d(s0); s1 = wred_d(s1); s2 = wred_d(s2);
    c0 = wred_u(c0); c1 = wred_u(c1); c2 = wred_u(c2);

    __shared__ double ls[4][3];
    __shared__ unsigned lc[4][3];
    int wid = threadIdx.x >> 6;
    int lane = threadIdx.x & 63;
    if (lane == 0) {
        ls[wid][0] = s0; ls[wid][1] = s1; ls[wid][2] = s2;
        lc[wid][0] = c0; lc[wid][1] = c1; lc[wid][2] = c2;
    }
    __syncthreads();
    if (threadIdx.x < 3) {
        int c = threadIdx.x;
        double s = ls[0][c] + ls[1][c] + ls[2][c] + ls[3][c];
        unsigned cc = lc[0][c] + lc[1][c] + lc[2][c] + lc[3][c];
        psum[blockIdx.x * 3 + c] = s;
        pcnt[blockIdx.x * 3 + c] = cc;
    }
}

// Every block: reduce partials -> mean[3] (L2/L3-hit), then scatter 8 pix/thr.
__global__ __launch_bounds__(256) void scatter_k(const double* __restrict__ psum,
                                                 const unsigned* __restrict__ pcnt,
                                                 const unsigned short* __restrict__ codes2,
                                                 float* __restrict__ out,
                                                 int nblk, int npix8) {
    // --- phase 1: redundant mean computation ---
    double s0 = 0.0, s1 = 0.0, s2 = 0.0;
    unsigned c0 = 0, c1 = 0, c2 = 0;
    for (int i = threadIdx.x; i < nblk; i += 256) {
        s0 += psum[i * 3 + 0]; s1 += psum[i * 3 + 1]; s2 += psum[i * 3 + 2];
        c0 += pcnt[i * 3 + 0]; c1 += pcnt[i * 3 + 1]; c2 += pcnt[i * 3 + 2];
    }
    s0 = wred_d(s0); s1 = wred_d(s1); s2 = wred_d(s2);
    c0 = wred_u(c0); c1 = wred_u(c1); c2 = wred_u(c2);

    __shared__ double ls[4][3];
    __shared__ unsigned lc[4][3];
    __shared__ float lmean[3];
    int wid = threadIdx.x >> 6;
    int lane = threadIdx.x & 63;
    if (lane == 0) {
        ls[wid][0] = s0; ls[wid][1] = s1; ls[wid][2] = s2;
        lc[wid][0] = c0; lc[wid][1] = c1; lc[wid][2] = c2;
    }
    __syncthreads();
    if (threadIdx.x < 3) {
        int c = threadIdx.x;
        double s = ls[0][c] + ls[1][c] + ls[2][c] + ls[3][c];
        unsigned cc = lc[0][c] + lc[1][c] + lc[2][c] + lc[3][c];
        // count includes the 3-channel broadcast in the reference
        lmean[c] = (float)(s / (3.0 * (double)cc));
    }
    __syncthreads();
    float m0 = lmean[0], m1 = lmean[1], m2 = lmean[2];

    // --- phase 2: scatter, 8 pixels (2 code bytes, 24 floats) per thread ---
    int tid = blockIdx.x * 256 + threadIdx.x;
    int stride = gridDim.x * 256;
    for (int i = tid; i < npix8; i += stride) {
        unsigned cc8 = codes2[i];
        float v[8];
#pragma unroll
        for (int p = 0; p < 8; ++p) {
            unsigned k = (cc8 >> (2 * p)) & 3;
            v[p] = (k == 1) ? m1 : ((k == 2) ? m2 : m0);
        }
        vfloat4* o = (vfloat4*)(out + (size_t)i * 24);
        vfloat4 o0 = {v[0], v[0], v[0], v[1]};
        vfloat4 o1 = {v[1], v[1], v[2], v[2]};
        vfloat4 o2 = {v[2], v[3], v[3], v[3]};
        vfloat4 o3 = {v[4], v[4], v[4], v[5]};
        vfloat4 o4 = {v[5], v[5], v[6], v[6]};
        vfloat4 o5 = {v[6], v[7], v[7], v[7]};
        o[0] = o0; o[1] = o1; o[2] = o2; o[3] = o3; o[4] = o4; o[5] = o5;
    }
}

extern "C" void kernel_launch(void* const* d_in, const int* in_sizes, int n_in,
                              void* d_out, int out_size, void* d_ws, size_t ws_size,
                              hipStream_t stream) {
    const float* feats = (const float*)d_in[0];
    const int* inst = (const int*)d_in[1];
    float* out = (float*)d_out;

    int npix = in_sizes[1];        // 16*1024*1024, divisible by 8
    int npix8 = npix >> 3;

    double* psum = (double*)d_ws;                          // RBLK*3 doubles
    unsigned* pcnt = (unsigned*)(psum + RBLK * 3);         // RBLK*3 uints
    unsigned short* codes2 = (unsigned short*)(pcnt + RBLK * 3);  // npix8*2 B (4 MB)

    reduce_k<<<RBLK, 256, 0, stream>>>(feats, inst, psum, pcnt, codes2, npix8);
    scatter_k<<<RBLK, 256, 0, stream>>>(psum, pcnt, codes2, out, RBLK, npix8);
}